// Round 3
// baseline (2302.097 us; speedup 1.0000x reference)
//
#include <hip/hip_runtime.h>
#include <hip/hip_bf16.h>

#define TLEN 2048
#define BSZ  2048

typedef float f32x4 __attribute__((ext_vector_type(4)));
typedef short bf16x8 __attribute__((ext_vector_type(8)));

__device__ __forceinline__ unsigned short f2b(float f) {
    union { __hip_bfloat16 h; unsigned short u; } v;
    v.h = __float2bfloat16(f);             // HW cvt, RNE
    return v.u;
}

// k-slot permutation: frag slot (g,e) of K-tile kk holds k = sigma_k(kk,g,e).
// Chosen so the D-output registers of the previous (transposed) layer land
// exactly in their own lane's next-layer B-frag slots: D of Mt=2kk gives cols
// 32kk+4g+i (-> e=0..3), Mt=2kk+1 gives 32kk+16+4g+i (-> e=4..7). Bijective.
// Weights (A-side) are loaded with the same sigma in the prologue.
__device__ __forceinline__ constexpr int sigma_k(int kk, int g, int e) {
    return 32*kk + ((e < 4) ? (4*g + e) : (16 + 4*g + (e - 4)));
}

// LeakyReLU(0.1) + pack two f32x4 D-regs into one bf16x8 B-frag
__device__ __forceinline__ bf16x8 leaky_pack(f32x4 lo, f32x4 hi) {
    bf16x8 r;
    #pragma unroll
    for (int i = 0; i < 4; ++i) {
        float x = lo[i]; x = fmaxf(x, 0.1f * x);
        ((unsigned short*)&r)[i] = f2b(x);
        float y = hi[i]; y = fmaxf(y, 0.1f * y);
        ((unsigned short*)&r)[4 + i] = f2b(y);
    }
    return r;
}

__global__ __launch_bounds__(64, 1) void garch_scan_kernel(
    const float* __restrict__ returns, const float* __restrict__ log_rv,
    const float* __restrict__ p_omega, const float* __restrict__ p_beta,
    const float* __restrict__ p_tau1,  const float* __restrict__ p_tau2,
    const float* __restrict__ p_gamma, const float* __restrict__ p_xi,
    const float* __restrict__ p_phi,   const float* __restrict__ p_delta1,
    const float* __restrict__ p_delta2,const float* __restrict__ p_mu,
    const float* __restrict__ W1, const float* __restrict__ b1,
    const float* __restrict__ W2, const float* __restrict__ b2,
    const float* __restrict__ W3, const float* __restrict__ b3,
    const float* __restrict__ W4, const float* __restrict__ b4,
    float* __restrict__ out)
{
    const int lane = threadIdx.x;          // one wave per block
    const int c16  = lane & 15;            // batch row within tile (N dim)
    const int g    = lane >> 4;            // 4-row group (M dim rows 4g+i)

    const float omega = p_omega[0], beta = p_beta[0], tau1 = p_tau1[0],
                tau2 = p_tau2[0],  gma  = p_gamma[0], xi  = p_xi[0],
                phi  = p_phi[0],   d1   = p_delta1[0], d2 = p_delta2[0],
                mu   = p_mu[0],    b4s  = b4[0];

    const int grow = blockIdx.x * 16 + c16;
    const size_t row_off = (size_t)grow * TLEN;

    // ---------------- prologue: all weights/biases -> registers ----------------
    // Transposed orientation: A[m=out-col][k] = W[k][m], B[k][n=batch] = act[n][k].
    bf16x8 w1f[8];        // L1: 8 M-tiles, K=32 (k<5 live), sigma1(g,e)=8g+e
    bf16x8 w2f[8][4];     // L2: 8 M-tiles x 4 K-tiles (sigma_k)
    bf16x8 w3f[4][4];     // L3: 4 M-tiles x 4 K-tiles (sigma_k)
    bf16x8 w4f[2];        // L4: W4 replicated over all 16 m-rows, K=64 (sigma_k)
    f32x4 b1v[8], b2v[8], b3v[4];

    #pragma unroll
    for (int Mt = 0; Mt < 8; ++Mt) {
        const int m = 16*Mt + c16;
        #pragma unroll
        for (int e = 0; e < 8; ++e) {
            const int k = 8*g + e;                       // sigma1 = standard slotting
            ((unsigned short*)&w1f[Mt])[e] = (k < 5) ? f2b(W1[k*128 + m]) : (unsigned short)0;
        }
        #pragma unroll
        for (int kk = 0; kk < 4; ++kk) {
            #pragma unroll
            for (int e = 0; e < 8; ++e)
                ((unsigned short*)&w2f[Mt][kk])[e] = f2b(W2[sigma_k(kk,g,e)*128 + m]);
        }
        #pragma unroll
        for (int i = 0; i < 4; ++i) {
            b1v[Mt][i] = b1[16*Mt + 4*g + i];            // bias per out-col, via C-operand
            b2v[Mt][i] = b2[16*Mt + 4*g + i];
        }
    }
    #pragma unroll
    for (int Mt = 0; Mt < 4; ++Mt) {
        const int m = 16*Mt + c16;
        #pragma unroll
        for (int kk = 0; kk < 4; ++kk) {
            #pragma unroll
            for (int e = 0; e < 8; ++e)
                ((unsigned short*)&w3f[Mt][kk])[e] = f2b(W3[sigma_k(kk,g,e)*64 + m]);
        }
        #pragma unroll
        for (int i = 0; i < 4; ++i) b3v[Mt][i] = b3[16*Mt + 4*g + i];
    }
    #pragma unroll
    for (int kk = 0; kk < 2; ++kk) {
        #pragma unroll
        for (int e = 0; e < 8; ++e)
            ((unsigned short*)&w4f[kk])[e] = f2b(W4[sigma_k(kk,g,e)]);   // same for all m-rows
    }

    // ---------------- scan state ----------------
    float lh_c = 0.f;     // enh(t-1)
    float nb   = 0.f;     // omega + tau1*z + tau2*(z^2-1) + gamma*lx from t-1
    float r_cur   = returns[row_off];
    float lrv_cur = log_rv[row_off];
    int ti = 0, di = 0;   // t % 78, (t/78) % 5

    for (int t = 0; t < TLEN; ++t) {
        // prefetch next inputs (L2/L3-resident; latency hidden under the step)
        const int tn = (t + 1 < TLEN) ? t + 1 : t;
        const float r_nxt   = returns[row_off + tn];
        const float lrv_nxt = log_rv[row_off + tn];

        // ---- recurrence (fp32, per-lane row c16, replicated over g) ----
        float lh;
        if (t == 0) lh = lrv_cur;                        // log(exp(lrv)) == lrv
        else        lh = fmaf(beta, lh_c, nb);
        const float zv = (r_cur - mu) * __expf(-0.5f * lh);
        const float zz = fmaf(zv, zv, -1.f);
        const float lx = xi + phi*lh + d1*zv + d2*zz;
        const float uv = lrv_cur - lx;
        nb = omega + tau1*zv + tau2*zz + gma*lx;         // for t+1 (off critical chain)
        const float pre = fmaf(0.01f, b4s, lh);          // lh + 0.01*b4

        // ---- feature B-frag: slot (0,e)=feature e (sigma1), rest zero ----
        bf16x8 fb = {0,0,0,0,0,0,0,0};
        if (g == 0) {
            unsigned short* fp = (unsigned short*)&fb;
            fp[0] = f2b(lh); fp[1] = f2b(zv); fp[2] = f2b(uv);
            fp[3] = f2b((float)ti * (1.f/77.f)); fp[4] = f2b((float)di * 0.25f);
        }

        // ---- L1: h1^T = W1^T(128x5) . feat^T(5x16), 8 independent MFMAs ----
        f32x4 acc1[8];
        #pragma unroll
        for (int Mt = 0; Mt < 8; ++Mt)
            acc1[Mt] = __builtin_amdgcn_mfma_f32_16x16x32_bf16(w1f[Mt], fb, b1v[Mt], 0,0,0);

        bf16x8 p1[4];                                    // D-pairs -> B-frags, in-lane
        #pragma unroll
        for (int kk = 0; kk < 4; ++kk) p1[kk] = leaky_pack(acc1[2*kk], acc1[2*kk+1]);

        // ---- L2: 8 M-tiles x 4 K-tiles ----
        f32x4 acc2[8];
        #pragma unroll
        for (int Mt = 0; Mt < 8; ++Mt) {
            f32x4 a = b2v[Mt];
            #pragma unroll
            for (int kk = 0; kk < 4; ++kk)
                a = __builtin_amdgcn_mfma_f32_16x16x32_bf16(w2f[Mt][kk], p1[kk], a, 0,0,0);
            acc2[Mt] = a;
        }
        bf16x8 p2[4];
        #pragma unroll
        for (int kk = 0; kk < 4; ++kk) p2[kk] = leaky_pack(acc2[2*kk], acc2[2*kk+1]);

        // ---- L3: 4 M-tiles x 4 K-tiles ----
        f32x4 acc3[4];
        #pragma unroll
        for (int Mt = 0; Mt < 4; ++Mt) {
            f32x4 a = b3v[Mt];
            #pragma unroll
            for (int kk = 0; kk < 4; ++kk)
                a = __builtin_amdgcn_mfma_f32_16x16x32_bf16(w3f[Mt][kk], p2[kk], a, 0,0,0);
            acc3[Mt] = a;
        }
        bf16x8 p3[2];
        #pragma unroll
        for (int kk = 0; kk < 2; ++kk) p3[kk] = leaky_pack(acc3[2*kk], acc3[2*kk+1]);

        // ---- L4: dot(h3,W4) as MFMA with W4 replicated over m-rows ----
        // K-dim does the 64-col reduction; every D reg equals the full dot.
        f32x4 z4 = {0.f, 0.f, 0.f, 0.f};
        f32x4 d4 = __builtin_amdgcn_mfma_f32_16x16x32_bf16(w4f[0], p3[0], z4, 0,0,0);
        d4 = __builtin_amdgcn_mfma_f32_16x16x32_bf16(w4f[1], p3[1], d4, 0,0,0);
        const float enh = fmaf(0.01f, d4[0], pre);

        // ---- outputs: lane's g picks the stream; every lane has all values ----
        const float ov = (g == 0) ? enh : (g == 1) ? lx : (g == 2) ? zv : uv;
        out[(size_t)g * (BSZ * (size_t)TLEN) + row_off + t] = ov;

        // ---- carry ----
        lh_c = enh;
        r_cur = r_nxt; lrv_cur = lrv_nxt;
        if (++ti == 78) { ti = 0; if (++di == 5) di = 0; }
    }
}

extern "C" void kernel_launch(void* const* d_in, const int* in_sizes, int n_in,
                              void* d_out, int out_size, void* d_ws, size_t ws_size,
                              hipStream_t stream) {
    (void)in_sizes; (void)n_in; (void)d_ws; (void)ws_size; (void)out_size;
    const float* returns = (const float*)d_in[0];
    const float* log_rv  = (const float*)d_in[1];
    const float* p_omega = (const float*)d_in[2];
    const float* p_beta  = (const float*)d_in[3];
    const float* p_tau1  = (const float*)d_in[4];
    const float* p_tau2  = (const float*)d_in[5];
    const float* p_gamma = (const float*)d_in[6];
    const float* p_xi    = (const float*)d_in[7];
    const float* p_phi   = (const float*)d_in[8];
    const float* p_d1    = (const float*)d_in[9];
    const float* p_d2    = (const float*)d_in[10];
    const float* p_mu    = (const float*)d_in[11];
    const float* W1 = (const float*)d_in[12];
    const float* b1 = (const float*)d_in[13];
    const float* W2 = (const float*)d_in[14];
    const float* b2 = (const float*)d_in[15];
    const float* W3 = (const float*)d_in[16];
    const float* b3 = (const float*)d_in[17];
    const float* W4 = (const float*)d_in[18];
    const float* b4 = (const float*)d_in[19];
    float* out = (float*)d_out;

    garch_scan_kernel<<<dim3(BSZ / 16), dim3(64), 0, stream>>>(
        returns, log_rv, p_omega, p_beta, p_tau1, p_tau2, p_gamma, p_xi,
        p_phi, p_d1, p_d2, p_mu, W1, b1, W2, b2, W3, b3, W4, b4, out);
}